// Round 1
// baseline (256.780 us; speedup 1.0000x reference)
//
#include <hip/hip_runtime.h>
#include <hip/hip_bf16.h>
#include <stdint.h>

typedef unsigned short u16;
typedef __attribute__((ext_vector_type(8))) short bf16x8;
typedef __attribute__((ext_vector_type(4))) float f32x4;

#define GLDS16(gsrc, ldst) \
  __builtin_amdgcn_global_load_lds((const __attribute__((address_space(1))) uint32_t*)(gsrc), \
                                   (__attribute__((address_space(3))) uint32_t*)(ldst), 16, 0, 0)

__device__ __forceinline__ u16 f2bf(float f) {
  unsigned u = __float_as_uint(f);
  unsigned r = (u + 0x7fffu + ((u >> 16) & 1u)) >> 16;
  return (u16)r;
}
__device__ __forceinline__ float bf2f(u16 v) {
  return __uint_as_float(((unsigned)v) << 16);
}

// ---------------- fp32 -> bf16 cast, 4 elems/thread ----------------
__global__ void cvt_f2b4(const float* __restrict__ in, u16* __restrict__ out, int n4) {
  int i = blockIdx.x * 256 + threadIdx.x;
  if (i < n4) {
    float4 v = ((const float4*)in)[i];
    ushort4 r;
    r.x = f2bf(v.x); r.y = f2bf(v.y); r.z = f2bf(v.z); r.w = f2bf(v.w);
    ((ushort4*)out)[i] = r;
  }
}

// ---------------- C = A @ B^T (+bias). A[M,K], Bm[N,K] bf16 K-major ----------------
// 128x128 tile, BK=32, 256 threads = 4 waves (2x2), each wave 64x64 (4x4 16x16 frags)
template<int OUT_BF16, int HAS_BIAS>
__global__ __launch_bounds__(256, 2)
void gemm_bt(const u16* __restrict__ A, const u16* __restrict__ Bm,
             const float* __restrict__ bias, void* __restrict__ Cout,
             int M, int N, int K)
{
  __shared__ __align__(16) u16 As[128 * 32];
  __shared__ __align__(16) u16 Bs[128 * 32];
  const int tid  = threadIdx.x;
  const int lane = tid & 63;
  const int w    = tid >> 6;
  const int wr   = w >> 1, wc = w & 1;
  const int m0 = blockIdx.x * 128;
  const int n0 = blockIdx.y * 128;

  f32x4 acc[4][4];
  for (int m = 0; m < 4; ++m)
    for (int n = 0; n < 4; ++n)
      acc[m][n] = (f32x4){0.f, 0.f, 0.f, 0.f};

  const int rsel = lane >> 2;       // row within 16-row staging segment
  const int koff = (lane & 3) * 8;  // k-element offset of this lane's 16B
  const int fr   = lane & 15;
  const int fk   = (lane >> 4) * 8;

  const int KT = K >> 5;
  for (int kt = 0; kt < KT; ++kt) {
    const int kbase = kt * 32;
#pragma unroll
    for (int t = 0; t < 2; ++t) {
      const int seg = w * 2 + t;
      const int rr = seg * 16 + rsel;
      GLDS16(A  + (size_t)(m0 + rr) * K + kbase + koff, (char*)As + seg * 1024);
      GLDS16(Bm + (size_t)(n0 + rr) * K + kbase + koff, (char*)Bs + seg * 1024);
    }
    __syncthreads();
    bf16x8 af[4], bg[4];
#pragma unroll
    for (int m = 0; m < 4; ++m)
      af[m] = *(const bf16x8*)(As + (wr * 64 + m * 16 + fr) * 32 + fk);
#pragma unroll
    for (int n = 0; n < 4; ++n)
      bg[n] = *(const bf16x8*)(Bs + (wc * 64 + n * 16 + fr) * 32 + fk);
#pragma unroll
    for (int m = 0; m < 4; ++m)
#pragma unroll
      for (int n = 0; n < 4; ++n)
        acc[m][n] = __builtin_amdgcn_mfma_f32_16x16x32_bf16(af[m], bg[n], acc[m][n], 0, 0, 0);
    __syncthreads();
  }

  // C/D layout: col = lane&15, row = (lane>>4)*4 + i   [guide m89/m91 verified]
  const int r0 = m0 + wr * 64 + (lane >> 4) * 4;
  const int c0 = n0 + wc * 64 + fr;
  float bv[4];
  if (HAS_BIAS) {
#pragma unroll
    for (int n = 0; n < 4; ++n) bv[n] = bias[c0 + n * 16];
  }
#pragma unroll
  for (int m = 0; m < 4; ++m)
#pragma unroll
    for (int n = 0; n < 4; ++n)
#pragma unroll
      for (int i = 0; i < 4; ++i) {
        const size_t idx = (size_t)(r0 + m * 16 + i) * N + (c0 + n * 16);
        if (OUT_BF16) ((u16*)Cout)[idx] = f2bf(acc[m][n][i]);
        else          ((float*)Cout)[idx] = acc[m][n][i] + (HAS_BIAS ? bv[n] : 0.f);
      }
}

// ---------------- per-(b,h,n) standardization of q,k rows (D=64, ddof=1) ----------------
// qkv layout [B*N, 2304], col = s*768 + h*64 + d. One wave per row; lane = d.
__global__ void norm_qk(const u16* __restrict__ qkv, u16* __restrict__ q, u16* __restrict__ k) {
  const int lane = threadIdx.x & 63;
  const int w = threadIdx.x >> 6;
  const int r = blockIdx.x * 4 + w;          // 0 .. B*H*N-1
  const int b = r / 12288;
  const int rem = r - b * 12288;
  const int h = rem >> 10;
  const int n = rem & 1023;
  const size_t rowbase = (size_t)(b * 1024 + n) * 2304 + h * 64 + lane;
  const size_t obase = ((size_t)(b * 12 + h) * 1024 + n) * 64 + lane;
#pragma unroll
  for (int s = 0; s < 2; ++s) {
    float t = bf2f(qkv[rowbase + (size_t)s * 768]);
    float sum = t;
#pragma unroll
    for (int m = 1; m < 64; m <<= 1) sum += __shfl_xor(sum, m, 64);
    float mu = sum * (1.f / 64.f);
    float d = t - mu;
    float ss = d * d;
#pragma unroll
    for (int m = 1; m < 64; m <<= 1) ss += __shfl_xor(ss, m, 64);
    float outv = d * rsqrtf(ss * (1.f / 63.f));
    (s == 0 ? q : k)[obase] = f2bf(outv);
  }
}

// ---------------- V: [B,H,N,D] slice of qkv -> vt[B,H,D,N] ----------------
__global__ void transpose_v(const u16* __restrict__ qkv, u16* __restrict__ vt) {
  __shared__ u16 tile[64][65];
  const int bid = blockIdx.x;          // = bh*16 + nt
  const int nt = bid & 15;
  const int bh = bid >> 4;
  const int b = bh / 12, h = bh % 12;
  const int tx = threadIdx.x & 63;
  const int ty = threadIdx.x >> 6;
#pragma unroll
  for (int i = 0; i < 16; ++i) {
    const int n = i * 4 + ty;
    tile[n][tx] = qkv[(size_t)(b * 1024 + nt * 64 + n) * 2304 + 1536 + h * 64 + tx];
  }
  __syncthreads();
#pragma unroll
  for (int i = 0; i < 16; ++i) {
    const int d = i * 4 + ty;
    vt[((size_t)(bh * 64 + d)) * 1024 + nt * 64 + tx] = tile[tx][d];
  }
}

// ---------------- flash attention (no max-sub; |logit| <= 7.875 guaranteed) ----------------
// block = (b,h,qt): 4 waves, wave handles 16 q-rows x 64 d. Key tiles of 64.
__global__ __launch_bounds__(256, 2)
void attn_fwd(const u16* __restrict__ q, const u16* __restrict__ k,
              const u16* __restrict__ vt, u16* __restrict__ out)
{
  __shared__ __align__(16) u16 Ks[64 * 64];    // [key][d]
  __shared__ __align__(16) u16 VTs[64 * 64];   // [d][key]
  __shared__ __align__(16) u16 Ps[4][16 * 64]; // per-wave P [qrow][key]
  const int tid = threadIdx.x, lane = tid & 63, w = tid >> 6;
  const int qt = blockIdx.x & 15;
  const int bh = blockIdx.x >> 4;
  const int b = bh / 12, h = bh % 12;
  const int fr = lane & 15;
  const int fk = (lane >> 4) * 8;

  // Q fragments held in registers for the whole kernel
  bf16x8 aq[2];
  {
    const int qrow = qt * 64 + w * 16 + fr;
    const u16* qp = q + ((size_t)bh * 1024 + qrow) * 64;
#pragma unroll
    for (int kk = 0; kk < 2; ++kk)
      aq[kk] = *(const bf16x8*)(qp + kk * 32 + fk);
  }

  f32x4 o[4];
  for (int n = 0; n < 4; ++n) o[n] = (f32x4){0.f, 0.f, 0.f, 0.f};
  float rs[4] = {0.f, 0.f, 0.f, 0.f};

  const int srow = lane >> 3;           // staging row within 8-row segment
  const int schunk = (lane & 7) * 8;    // staging k-chunk

  for (int kt = 0; kt < 16; ++kt) {
#pragma unroll
    for (int t = 0; t < 2; ++t) {
      const int seg = w * 2 + t;
      const int rr = seg * 8 + srow;
      GLDS16(k  + ((size_t)bh * 1024 + kt * 64 + rr) * 64 + schunk, (char*)Ks  + seg * 1024);
      GLDS16(vt + ((size_t)bh * 64 + rr) * 1024 + kt * 64 + schunk, (char*)VTs + seg * 1024);
    }
    __syncthreads();

    // S = Q @ K^T  (16 q-rows x 64 keys per wave)
    f32x4 s[4];
#pragma unroll
    for (int n = 0; n < 4; ++n) s[n] = (f32x4){0.f, 0.f, 0.f, 0.f};
#pragma unroll
    for (int n = 0; n < 4; ++n)
#pragma unroll
      for (int kk = 0; kk < 2; ++kk) {
        bf16x8 bk = *(const bf16x8*)(Ks + (n * 16 + fr) * 64 + kk * 32 + fk);
        s[n] = __builtin_amdgcn_mfma_f32_16x16x32_bf16(aq[kk], bk, s[n], 0, 0, 0);
      }

    // P = exp(S/8); accumulate row sums; write P to per-wave LDS (layout change for PV A-frag)
#pragma unroll
    for (int n = 0; n < 4; ++n)
#pragma unroll
      for (int i = 0; i < 4; ++i) {
        float p = __expf(s[n][i] * 0.125f);
        rs[i] += p;
        Ps[w][((lane >> 4) * 4 + i) * 64 + n * 16 + fr] = f2bf(p);
      }

    // O += P @ V   (same-wave LDS RAW: DS pipe is in-order, no barrier needed)
#pragma unroll
    for (int kk = 0; kk < 2; ++kk) {
      bf16x8 ap = *(const bf16x8*)(&Ps[w][fr * 64 + kk * 32 + fk]);
#pragma unroll
      for (int n = 0; n < 4; ++n) {
        bf16x8 bv = *(const bf16x8*)(VTs + (n * 16 + fr) * 64 + kk * 32 + fk);
        o[n] = __builtin_amdgcn_mfma_f32_16x16x32_bf16(ap, bv, o[n], 0, 0, 0);
      }
    }
    __syncthreads();
  }

  // rowsum: reduce across the 16 lanes sharing (lane>>4)
  float inv[4];
#pragma unroll
  for (int i = 0; i < 4; ++i) {
    float v = rs[i];
    v += __shfl_xor(v, 1, 64);
    v += __shfl_xor(v, 2, 64);
    v += __shfl_xor(v, 4, 64);
    v += __shfl_xor(v, 8, 64);
    inv[i] = 1.f / v;
  }
  const int orow0 = qt * 64 + w * 16 + (lane >> 4) * 4;
#pragma unroll
  for (int n = 0; n < 4; ++n)
#pragma unroll
    for (int i = 0; i < 4; ++i)
      out[((size_t)b * 1024 + orow0 + i) * 768 + h * 64 + n * 16 + fr] = f2bf(o[n][i] * inv[i]);
}

// ---------------- launch ----------------
extern "C" void kernel_launch(void* const* d_in, const int* in_sizes, int n_in,
                              void* d_out, int out_size, void* d_ws, size_t ws_size,
                              hipStream_t stream)
{
  (void)in_sizes; (void)n_in; (void)out_size; (void)ws_size;
  const float* x      = (const float*)d_in[0];
  const float* qkv_w  = (const float*)d_in[1];
  const float* proj_w = (const float*)d_in[2];
  const float* proj_b = (const float*)d_in[3];
  float* out = (float*)d_out;

  char* p = (char*)d_ws;
  auto take = [&](size_t bytes) { char* r = p; p += (bytes + 255) & ~(size_t)255; return r; };
  u16* xb   = (u16*)take((size_t)8192 * 768 * 2);   // x bf16
  u16* wqb  = (u16*)take((size_t)2304 * 768 * 2);   // qkv_w bf16
  u16* wpb  = (u16*)take((size_t)768 * 768 * 2);    // proj_w bf16
  u16* qkvb = (u16*)take((size_t)8192 * 2304 * 2);  // qkv bf16 [B*N, 2304]
  u16* qb   = (u16*)take((size_t)8192 * 768 * 2);   // q norm  [B,H,N,D]
  u16* kb   = (u16*)take((size_t)8192 * 768 * 2);   // k norm  [B,H,N,D]
  u16* vtb  = (u16*)take((size_t)8192 * 768 * 2);   // v^T     [B,H,D,N]
  u16* aob  = (u16*)take((size_t)8192 * 768 * 2);   // attn out [B*N, C]

  cvt_f2b4<<<6144, 256, 0, stream>>>(x, xb, 8192 * 768 / 4);
  cvt_f2b4<<<1728, 256, 0, stream>>>(qkv_w, wqb, 2304 * 768 / 4);
  cvt_f2b4<<<576,  256, 0, stream>>>(proj_w, wpb, 768 * 768 / 4);

  gemm_bt<1, 0><<<dim3(64, 18), 256, 0, stream>>>(xb, wqb, nullptr, qkvb, 8192, 2304, 768);
  norm_qk<<<24576, 256, 0, stream>>>(qkvb, qb, kb);
  transpose_v<<<1536, 256, 0, stream>>>(qkvb, vtb);
  attn_fwd<<<1536, 256, 0, stream>>>(qb, kb, vtb, aob);
  gemm_bt<0, 1><<<dim3(64, 6), 256, 0, stream>>>(aob, wpb, proj_b, out, 8192, 768, 768);
}

// Round 3
// 233.421 us; speedup vs baseline: 1.1001x; 1.1001x over previous
//
#include <hip/hip_runtime.h>
#include <hip/hip_bf16.h>
#include <stdint.h>

typedef unsigned short u16;
typedef __attribute__((ext_vector_type(8))) short bf16x8;
typedef __attribute__((ext_vector_type(4))) float f32x4;

#define GLDS16(gsrc, ldst) \
  __builtin_amdgcn_global_load_lds((const __attribute__((address_space(1))) uint32_t*)(gsrc), \
                                   (__attribute__((address_space(3))) uint32_t*)(ldst), 16, 0, 0)

__device__ __forceinline__ u16 f2bf(float f) {
  unsigned u = __float_as_uint(f);
  unsigned r = (u + 0x7fffu + ((u >> 16) & 1u)) >> 16;
  return (u16)r;
}
__device__ __forceinline__ float bf2f(u16 v) {
  return __uint_as_float(((unsigned)v) << 16);
}

// ---------------- fp32 -> bf16 cast, 4 elems/thread ----------------
__global__ void cvt_f2b4(const float* __restrict__ in, u16* __restrict__ out, int n4) {
  int i = blockIdx.x * 256 + threadIdx.x;
  if (i < n4) {
    float4 v = ((const float4*)in)[i];
    ushort4 r;
    r.x = f2bf(v.x); r.y = f2bf(v.y); r.z = f2bf(v.z); r.w = f2bf(v.w);
    ((ushort4*)out)[i] = r;
  }
}

// ---------------- C = A @ B^T (+bias). A[M,K], Bm[N,K] bf16 K-major ----------------
// 128x128 tile, BK=32, 256 threads = 4 waves (2x2), each wave 64x64 (4x4 16x16 frags)
template<int OUT_BF16, int HAS_BIAS>
__global__ __launch_bounds__(256, 2)
void gemm_bt(const u16* __restrict__ A, const u16* __restrict__ Bm,
             const float* __restrict__ bias, void* __restrict__ Cout,
             int M, int N, int K)
{
  __shared__ __align__(16) u16 As[128 * 32];
  __shared__ __align__(16) u16 Bs[128 * 32];
  const int tid  = threadIdx.x;
  const int lane = tid & 63;
  const int w    = tid >> 6;
  const int wr   = w >> 1, wc = w & 1;
  const int m0 = blockIdx.x * 128;
  const int n0 = blockIdx.y * 128;

  f32x4 acc[4][4];
  for (int m = 0; m < 4; ++m)
    for (int n = 0; n < 4; ++n)
      acc[m][n] = (f32x4){0.f, 0.f, 0.f, 0.f};

  const int rsel = lane >> 2;       // row within 16-row staging segment
  const int koff = (lane & 3) * 8;  // k-element offset of this lane's 16B
  const int fr   = lane & 15;
  const int fk   = (lane >> 4) * 8;

  const int KT = K >> 5;
  for (int kt = 0; kt < KT; ++kt) {
    const int kbase = kt * 32;
#pragma unroll
    for (int t = 0; t < 2; ++t) {
      const int seg = w * 2 + t;
      const int rr = seg * 16 + rsel;
      GLDS16(A  + (size_t)(m0 + rr) * K + kbase + koff, (char*)As + seg * 1024);
      GLDS16(Bm + (size_t)(n0 + rr) * K + kbase + koff, (char*)Bs + seg * 1024);
    }
    __syncthreads();
    bf16x8 af[4], bg[4];
#pragma unroll
    for (int m = 0; m < 4; ++m)
      af[m] = *(const bf16x8*)(As + (wr * 64 + m * 16 + fr) * 32 + fk);
#pragma unroll
    for (int n = 0; n < 4; ++n)
      bg[n] = *(const bf16x8*)(Bs + (wc * 64 + n * 16 + fr) * 32 + fk);
#pragma unroll
    for (int m = 0; m < 4; ++m)
#pragma unroll
      for (int n = 0; n < 4; ++n)
        acc[m][n] = __builtin_amdgcn_mfma_f32_16x16x32_bf16(af[m], bg[n], acc[m][n], 0, 0, 0);
    __syncthreads();
  }

  // C/D layout: col = lane&15, row = (lane>>4)*4 + i   [guide m89/m91 verified]
  const int r0 = m0 + wr * 64 + (lane >> 4) * 4;
  const int c0 = n0 + wc * 64 + fr;
  float bv[4];
  if (HAS_BIAS) {
#pragma unroll
    for (int n = 0; n < 4; ++n) bv[n] = bias[c0 + n * 16];
  }
#pragma unroll
  for (int m = 0; m < 4; ++m)
#pragma unroll
    for (int n = 0; n < 4; ++n)
#pragma unroll
      for (int i = 0; i < 4; ++i) {
        const size_t idx = (size_t)(r0 + m * 16 + i) * N + (c0 + n * 16);
        if (OUT_BF16) ((u16*)Cout)[idx] = f2bf(acc[m][n][i]);
        else          ((float*)Cout)[idx] = acc[m][n][i] + (HAS_BIAS ? bv[n] : 0.f);
      }
}

// ---------------- per-(b,h,n) standardization of q,k rows (D=64, ddof=1) ----------------
__global__ void norm_qk(const u16* __restrict__ qkv, u16* __restrict__ q, u16* __restrict__ k) {
  const int lane = threadIdx.x & 63;
  const int w = threadIdx.x >> 6;
  const int r = blockIdx.x * 4 + w;          // 0 .. B*H*N-1
  const int b = r / 12288;
  const int rem = r - b * 12288;
  const int h = rem >> 10;
  const int n = rem & 1023;
  const size_t rowbase = (size_t)(b * 1024 + n) * 2304 + h * 64 + lane;
  const size_t obase = ((size_t)(b * 12 + h) * 1024 + n) * 64 + lane;
#pragma unroll
  for (int s = 0; s < 2; ++s) {
    float t = bf2f(qkv[rowbase + (size_t)s * 768]);
    float sum = t;
#pragma unroll
    for (int m = 1; m < 64; m <<= 1) sum += __shfl_xor(sum, m, 64);
    float mu = sum * (1.f / 64.f);
    float d = t - mu;
    float ss = d * d;
#pragma unroll
    for (int m = 1; m < 64; m <<= 1) ss += __shfl_xor(ss, m, 64);
    float outv = d * rsqrtf(ss * (1.f / 63.f));
    (s == 0 ? q : k)[obase] = f2bf(outv);
  }
}

// ---------------- V: [B,H,N,D] slice of qkv -> vt[B,H,D,N] ----------------
__global__ void transpose_v(const u16* __restrict__ qkv, u16* __restrict__ vt) {
  __shared__ u16 tile[64][65];
  const int bid = blockIdx.x;          // = bh*16 + nt
  const int nt = bid & 15;
  const int bh = bid >> 4;
  const int b = bh / 12, h = bh % 12;
  const int tx = threadIdx.x & 63;
  const int ty = threadIdx.x >> 6;
#pragma unroll
  for (int i = 0; i < 16; ++i) {
    const int n = i * 4 + ty;
    tile[n][tx] = qkv[(size_t)(b * 1024 + nt * 64 + n) * 2304 + 1536 + h * 64 + tx];
  }
  __syncthreads();
#pragma unroll
  for (int i = 0; i < 16; ++i) {
    const int d = i * 4 + ty;
    vt[((size_t)(bh * 64 + d)) * 1024 + nt * 64 + tx] = tile[tx][d];
  }
}

// ---------------- flash attention (no max-sub; |logit| <= 7.875 guaranteed) ----------------
// block = (b,h,qt): 4 waves, wave handles 16 q-rows x 64 d. Key tiles of 64.
// LDS tiles XOR-swizzled: chunk c (16B) of row r lives at slot c ^ (r&7).
// global_load_lds dest stays linear; global SOURCE chunk is pre-swizzled (rule #21).
// K/V double-buffered, ONE barrier per tile (stage next overlaps compute of current).
__global__ __launch_bounds__(256, 2)
void attn_fwd(const u16* __restrict__ q, const u16* __restrict__ k,
              const u16* __restrict__ vt, u16* __restrict__ out)
{
  __shared__ __align__(16) u16 Ks[2][64 * 64];    // [key][d], swizzled
  __shared__ __align__(16) u16 VTs[2][64 * 64];   // [d][key], swizzled
  __shared__ __align__(16) u16 Ps[4][16 * 64];    // per-wave P [qrow][key], swizzled
  const int tid = threadIdx.x, lane = tid & 63, w = tid >> 6;
  // XCD-aware chunked swizzle: 1536 blocks % 8 == 0 -> 192 consecutive per XCD;
  // the 16 q-tiles of one (b,h) share an XCD's L2 for K/V.
  const int bid = (blockIdx.x & 7) * 192 + (blockIdx.x >> 3);
  const int qt = bid & 15;
  const int bh = bid >> 4;
  const int b = bh / 12, h = bh % 12;
  const int fr = lane & 15;
  const int hi = lane >> 4;
  const int fk = hi * 8;

  // Q fragments held in registers for the whole kernel
  bf16x8 aq[2];
  {
    const int qrow = qt * 64 + w * 16 + fr;
    const u16* qp = q + ((size_t)bh * 1024 + qrow) * 64;
#pragma unroll
    for (int kk = 0; kk < 2; ++kk)
      aq[kk] = *(const bf16x8*)(qp + kk * 32 + fk);
  }

  f32x4 o[4];
  for (int n = 0; n < 4; ++n) o[n] = (f32x4){0.f, 0.f, 0.f, 0.f};
  float rs[4] = {0.f, 0.f, 0.f, 0.f};

  const int srow = lane >> 3;                       // row within 8-row staging segment
  const int sc   = ((lane & 7) ^ srow) * 8;         // pre-swizzled source chunk (elems)
  const u16* kg = k  + (size_t)bh * 65536;          // [1024][64]
  const u16* vg = vt + (size_t)bh * 65536;          // [64][1024]

  auto stage = [&](int buf, int kt) {
#pragma unroll
    for (int t = 0; t < 2; ++t) {
      const int seg = w * 2 + t;
      const int rr = seg * 8 + srow;
      GLDS16(kg + (size_t)(kt * 64 + rr) * 64 + sc,  (char*)Ks[buf]  + seg * 1024);
      GLDS16(vg + (size_t)rr * 1024 + kt * 64 + sc,  (char*)VTs[buf] + seg * 1024);
    }
  };

  int cur = 0;
  stage(0, 0);
  for (int kt = 0; kt < 16; ++kt) {
    __syncthreads();                 // compiler drains vmcnt here -> buf[cur] ready
    if (kt < 15) stage(cur ^ 1, kt + 1);   // prefetch overlaps compute below

    // S = Q @ K^T  (16 q-rows x 64 keys per wave)
    f32x4 s[4];
#pragma unroll
    for (int n = 0; n < 4; ++n) s[n] = (f32x4){0.f, 0.f, 0.f, 0.f};
#pragma unroll
    for (int n = 0; n < 4; ++n)
#pragma unroll
      for (int kk = 0; kk < 2; ++kk) {
        bf16x8 bk = *(const bf16x8*)(Ks[cur] + (n * 16 + fr) * 64 + (((kk * 4 + hi) ^ (fr & 7)) * 8));
        s[n] = __builtin_amdgcn_mfma_f32_16x16x32_bf16(aq[kk], bk, s[n], 0, 0, 0);
      }

    // P = exp(S/8); row sums; write P swizzled to per-wave LDS
#pragma unroll
    for (int n = 0; n < 4; ++n)
#pragma unroll
      for (int i = 0; i < 4; ++i) {
        float p = __expf(s[n][i] * 0.125f);
        rs[i] += p;
        const int row = hi * 4 + i;
        const int swc = (n * 2 + (fr >> 3)) ^ (row & 7);
        Ps[w][row * 64 + swc * 8 + (fr & 7)] = f2bf(p);
      }

    // O += P @ V   (same-wave LDS RAW: in-order DS pipe, no barrier needed)
#pragma unroll
    for (int kk = 0; kk < 2; ++kk) {
      bf16x8 ap = *(const bf16x8*)(&Ps[w][fr * 64 + (((kk * 4 + hi) ^ (fr & 7)) * 8)]);
#pragma unroll
      for (int n = 0; n < 4; ++n) {
        bf16x8 bv = *(const bf16x8*)(VTs[cur] + (n * 16 + fr) * 64 + (((kk * 4 + hi) ^ (fr & 7)) * 8));
        o[n] = __builtin_amdgcn_mfma_f32_16x16x32_bf16(ap, bv, o[n], 0, 0, 0);
      }
    }
    cur ^= 1;
  }

  // rowsum: reduce across the 16 lanes sharing (lane>>4)
  float inv[4];
#pragma unroll
  for (int i = 0; i < 4; ++i) {
    float v = rs[i];
    v += __shfl_xor(v, 1, 64);
    v += __shfl_xor(v, 2, 64);
    v += __shfl_xor(v, 4, 64);
    v += __shfl_xor(v, 8, 64);
    inv[i] = 1.f / v;
  }
  const int orow0 = qt * 64 + w * 16 + (lane >> 4) * 4;
#pragma unroll
  for (int n = 0; n < 4; ++n)
#pragma unroll
    for (int i = 0; i < 4; ++i)
      out[((size_t)b * 1024 + orow0 + i) * 768 + h * 64 + n * 16 + fr] = f2bf(o[n][i] * inv[i]);
}

// ---------------- launch ----------------
extern "C" void kernel_launch(void* const* d_in, const int* in_sizes, int n_in,
                              void* d_out, int out_size, void* d_ws, size_t ws_size,
                              hipStream_t stream)
{
  (void)in_sizes; (void)n_in; (void)out_size; (void)ws_size;
  const float* x      = (const float*)d_in[0];
  const float* qkv_w  = (const float*)d_in[1];
  const float* proj_w = (const float*)d_in[2];
  const float* proj_b = (const float*)d_in[3];
  float* out = (float*)d_out;

  char* p = (char*)d_ws;
  auto take = [&](size_t bytes) { char* r = p; p += (bytes + 255) & ~(size_t)255; return r; };
  u16* xb   = (u16*)take((size_t)8192 * 768 * 2);   // x bf16
  u16* wqb  = (u16*)take((size_t)2304 * 768 * 2);   // qkv_w bf16
  u16* wpb  = (u16*)take((size_t)768 * 768 * 2);    // proj_w bf16
  u16* qkvb = (u16*)take((size_t)8192 * 2304 * 2);  // qkv bf16 [B*N, 2304]
  u16* qb   = (u16*)take((size_t)8192 * 768 * 2);   // q norm  [B,H,N,D]
  u16* kb   = (u16*)take((size_t)8192 * 768 * 2);   // k norm  [B,H,N,D]
  u16* vtb  = (u16*)take((size_t)8192 * 768 * 2);   // v^T     [B,H,D,N]
  u16* aob  = (u16*)take((size_t)8192 * 768 * 2);   // attn out [B*N, C]

  cvt_f2b4<<<6144, 256, 0, stream>>>(x, xb, 8192 * 768 / 4);
  cvt_f2b4<<<1728, 256, 0, stream>>>(qkv_w, wqb, 2304 * 768 / 4);
  cvt_f2b4<<<576,  256, 0, stream>>>(proj_w, wpb, 768 * 768 / 4);

  gemm_bt<1, 0><<<dim3(64, 18), 256, 0, stream>>>(xb, wqb, nullptr, qkvb, 8192, 2304, 768);
  norm_qk<<<24576, 256, 0, stream>>>(qkvb, qb, kb);
  transpose_v<<<1536, 256, 0, stream>>>(qkvb, vtb);
  attn_fwd<<<1536, 256, 0, stream>>>(qb, kb, vtb, aob);
  gemm_bt<0, 1><<<dim3(64, 6), 256, 0, stream>>>(aob, wpb, proj_b, out, 8192, 768, 768);
}

// Round 4
// 204.668 us; speedup vs baseline: 1.2546x; 1.1405x over previous
//
#include <hip/hip_runtime.h>
#include <hip/hip_bf16.h>
#include <stdint.h>

typedef unsigned short u16;
typedef __attribute__((ext_vector_type(8))) short bf16x8;
typedef __attribute__((ext_vector_type(4))) float f32x4;

#define GLDS16(gsrc, ldst) \
  __builtin_amdgcn_global_load_lds((const __attribute__((address_space(1))) uint32_t*)(gsrc), \
                                   (__attribute__((address_space(3))) uint32_t*)(ldst), 16, 0, 0)

__device__ __forceinline__ u16 f2bf(float f) {          // round-nearest-even (casts of inputs)
  unsigned u = __float_as_uint(f);
  return (u16)((u + 0x7fffu + ((u >> 16) & 1u)) >> 16);
}
__device__ __forceinline__ u16 f2bfr(float f) {         // cheap round-away (2 VALU ops)
  return (u16)((__float_as_uint(f) + 0x8000u) >> 16);
}
__device__ __forceinline__ float bf2f(u16 v) {
  return __uint_as_float(((unsigned)v) << 16);
}

// ---------------- fp32 -> bf16 cast, 4 elems/thread ----------------
__global__ void cvt_f2b4(const float* __restrict__ in, u16* __restrict__ out, int n4) {
  int i = blockIdx.x * 256 + threadIdx.x;
  if (i < n4) {
    float4 v = ((const float4*)in)[i];
    ushort4 r;
    r.x = f2bf(v.x); r.y = f2bf(v.y); r.z = f2bf(v.z); r.w = f2bf(v.w);
    ((ushort4*)out)[i] = r;
  }
}

// =====================================================================
// Shared GEMM K-loop pattern (K=768, KT=24): 128x128 tile, BK=32,
// 4 waves (2x2), TRIPLE-buffered LDS, raw s_barrier + counted vmcnt(4).
// Schedule (derived, per-thread FIFO vmcnt semantics):
//   prologue: stage(t0), stage(t1); vmcnt(4) [drains t0]; barrier
//   iter t:   stage(t+2) -> buf (t+2)%3 ; ds_read buf t%3 ; 16 MFMA ;
//             vmcnt(4) [drains t+1, leaves t+2 in flight] ; barrier
// Buffer (t+2)%3 was last read in iter t-1, whose end-barrier retired all
// readers before this iter's stage. One barrier per K-step, never vmcnt(0)
// until the tail.
// =====================================================================

#define GEMM_PREAMBLE(AP, BP)                                              \
  __shared__ __align__(16) u16 As[3][128 * 32];                            \
  __shared__ __align__(16) u16 Bs[3][128 * 32];                            \
  const int tid  = threadIdx.x;                                            \
  const int lane = tid & 63;                                               \
  const int w    = tid >> 6;                                               \
  const int wr   = w >> 1, wc = w & 1;                                     \
  const int m0 = blockIdx.x * 128;                                         \
  const int n0 = blockIdx.y * 128;                                         \
  f32x4 acc[4][4];                                                         \
  for (int m = 0; m < 4; ++m)                                              \
    for (int n = 0; n < 4; ++n) acc[m][n] = (f32x4){0.f, 0.f, 0.f, 0.f};   \
  const int rsel = lane >> 2;                                              \
  const int koff = (lane & 3) * 8;                                         \
  const int fr   = lane & 15;                                              \
  const int hi   = lane >> 4;                                              \
  const int fk   = hi * 8;                                                 \
  auto stage = [&](int buf, int kt) {                                      \
    _Pragma("unroll")                                                      \
    for (int t = 0; t < 2; ++t) {                                          \
      const int seg = w * 2 + t;                                           \
      const int rr  = seg * 16 + rsel;                                     \
      GLDS16(AP + (size_t)(m0 + rr) * 768 + kt * 32 + koff,                \
             (char*)As[buf] + seg * 1024);                                 \
      GLDS16(BP + (size_t)(n0 + rr) * 768 + kt * 32 + koff,                \
             (char*)Bs[buf] + seg * 1024);                                 \
    }                                                                      \
  };                                                                       \
  stage(0, 0); stage(1, 1);                                                \
  asm volatile("s_waitcnt vmcnt(4)" ::: "memory");                         \
  __builtin_amdgcn_s_barrier();                                            \
  for (int kt = 0; kt < 24; ++kt) {                                        \
    const int cb = kt % 3;                                                 \
    if (kt + 2 < 24) stage((kt + 2) % 3, kt + 2);                          \
    bf16x8 af[4], bg[4];                                                   \
    _Pragma("unroll")                                                      \
    for (int m = 0; m < 4; ++m)                                            \
      af[m] = *(const bf16x8*)(As[cb] + (wr * 64 + m * 16 + fr) * 32 + fk);\
    _Pragma("unroll")                                                      \
    for (int n = 0; n < 4; ++n)                                            \
      bg[n] = *(const bf16x8*)(Bs[cb] + (wc * 64 + n * 16 + fr) * 32 + fk);\
    _Pragma("unroll")                                                      \
    for (int m = 0; m < 4; ++m)                                            \
      _Pragma("unroll")                                                    \
      for (int n = 0; n < 4; ++n)                                          \
        acc[m][n] = __builtin_amdgcn_mfma_f32_16x16x32_bf16(af[m], bg[n], acc[m][n], 0, 0, 0); \
    if (kt < 23) {                                                         \
      if (kt < 22) asm volatile("s_waitcnt vmcnt(4)" ::: "memory");        \
      else         asm volatile("s_waitcnt vmcnt(0)" ::: "memory");        \
      __builtin_amdgcn_s_barrier();                                        \
    }                                                                      \
  }

// ---- qkv GEMM: A=xb[8192,768], B=wqb[2304,768]; epilogue scatters to
//      qraw[B,H,N,D], kraw[B,H,N,D], vt[B,H,D,N] (V transposed in-epilogue).
__global__ __launch_bounds__(256, 3)
void gemm_qkv(const u16* __restrict__ A, const u16* __restrict__ Bm,
              u16* __restrict__ qraw, u16* __restrict__ kraw, u16* __restrict__ vt)
{
  GEMM_PREAMBLE(A, Bm)
  // epilogue: block cols lie entirely in one section s (128 | 768)
  const int b     = m0 >> 10;
  const int nrow0 = (m0 & 1023) + wr * 64 + hi * 4;
  const int sec   = n0 / 768;                 // 0=q 1=k 2=v
  const int csb   = (n0 % 768) + wc * 64;
  u16* const secp = (sec == 0) ? qraw : (sec == 1) ? kraw : vt;
#pragma unroll
  for (int nf = 0; nf < 4; ++nf) {
    const int cs = csb + nf * 16;
    const int h  = cs >> 6;
    const int d  = (cs & 63) + fr;
    u16* base = secp + ((size_t)(b * 12 + h) << 16);
    if (sec < 2) {
#pragma unroll
      for (int m = 0; m < 4; ++m)
#pragma unroll
        for (int i = 0; i < 4; ++i)
          base[(size_t)(nrow0 + m * 16 + i) * 64 + d] = f2bfr(acc[m][nf][i]);
    } else {
#pragma unroll
      for (int m = 0; m < 4; ++m) {
        ushort4 pk;
        pk.x = f2bfr(acc[m][nf][0]); pk.y = f2bfr(acc[m][nf][1]);
        pk.z = f2bfr(acc[m][nf][2]); pk.w = f2bfr(acc[m][nf][3]);
        *(ushort4*)(base + (size_t)d * 1024 + nrow0 + m * 16) = pk;
      }
    }
  }
}

// ---- proj GEMM: A=aob[8192,768], B=wpb[768,768], +bias, fp32 out.
__global__ __launch_bounds__(256, 3)
void gemm_proj(const u16* __restrict__ A, const u16* __restrict__ Bm,
               const float* __restrict__ bias, float* __restrict__ Cout)
{
  GEMM_PREAMBLE(A, Bm)
  const int r0 = m0 + wr * 64 + hi * 4;
  const int c0 = n0 + wc * 64 + fr;
#pragma unroll
  for (int nf = 0; nf < 4; ++nf) {
    const float bv = bias[c0 + nf * 16];
#pragma unroll
    for (int m = 0; m < 4; ++m)
#pragma unroll
      for (int i = 0; i < 4; ++i)
        Cout[(size_t)(r0 + m * 16 + i) * 768 + c0 + nf * 16] = acc[m][nf][i] + bv;
  }
}

// ---------------- standardization (ddof=1), vectorized: 16 lanes/row ----------------
// rows of [B*H*N, 64]; lane = g*16+sub, each lane holds 4 dims (ushort4).
__global__ void norm_qk(const u16* __restrict__ qraw, const u16* __restrict__ kraw,
                        u16* __restrict__ q, u16* __restrict__ k)
{
  const int lane = threadIdx.x & 63, w = threadIdx.x >> 6;
  const int g = lane >> 4, sub = lane & 15;
  const int r = blockIdx.x * 16 + w * 4 + g;          // 0 .. 98303
  const size_t base = (size_t)r * 64 + sub * 4;
#pragma unroll
  for (int s = 0; s < 2; ++s) {
    const u16* src = s ? kraw : qraw;
    u16* dst = s ? k : q;
    ushort4 v = *(const ushort4*)(src + base);
    float f0 = bf2f(v.x), f1 = bf2f(v.y), f2 = bf2f(v.z), f3 = bf2f(v.w);
    float sum = f0 + f1 + f2 + f3;
    sum += __shfl_xor(sum, 1, 64); sum += __shfl_xor(sum, 2, 64);
    sum += __shfl_xor(sum, 4, 64); sum += __shfl_xor(sum, 8, 64);
    const float mu = sum * (1.f / 64.f);
    f0 -= mu; f1 -= mu; f2 -= mu; f3 -= mu;
    float ss = f0 * f0 + f1 * f1 + f2 * f2 + f3 * f3;
    ss += __shfl_xor(ss, 1, 64); ss += __shfl_xor(ss, 2, 64);
    ss += __shfl_xor(ss, 4, 64); ss += __shfl_xor(ss, 8, 64);
    const float sc = rsqrtf(ss * (1.f / 63.f));
    ushort4 o;
    o.x = f2bfr(f0 * sc); o.y = f2bfr(f1 * sc);
    o.z = f2bfr(f2 * sc); o.w = f2bfr(f3 * sc);
    *(ushort4*)(dst + base) = o;
  }
}

// ---------------- flash attention (no max-sub; |logit| <= 7.875 guaranteed) ----------------
// Unchanged structure from R1 (swizzled LDS, dbuf, XCD-chunked bid) plus:
//  - rowsum via ones-column MFMA (o5): kills 16 VALU adds/tile + epilogue shuffle-reduce,
//    and numerator/denominator use identically-rounded P.
//  - f2bfr (2-op) for P and output stores.
__global__ __launch_bounds__(256, 2)
void attn_fwd(const u16* __restrict__ q, const u16* __restrict__ k,
              const u16* __restrict__ vt, u16* __restrict__ out)
{
  __shared__ __align__(16) u16 Ks[2][64 * 64];
  __shared__ __align__(16) u16 VTs[2][64 * 64];
  __shared__ __align__(16) u16 Ps[4][16 * 64];
  const int tid = threadIdx.x, lane = tid & 63, w = tid >> 6;
  const int bid = (blockIdx.x & 7) * 192 + (blockIdx.x >> 3);
  const int qt = bid & 15;
  const int bh = bid >> 4;
  const int b = bh / 12, h = bh % 12;
  const int fr = lane & 15;
  const int hi = lane >> 4;
  const int fk = hi * 8;

  bf16x8 aq[2];
  {
    const int qrow = qt * 64 + w * 16 + fr;
    const u16* qp = q + ((size_t)bh * 1024 + qrow) * 64;
#pragma unroll
    for (int kk = 0; kk < 2; ++kk)
      aq[kk] = *(const bf16x8*)(qp + kk * 32 + fk);
  }

  bf16x8 ones;
#pragma unroll
  for (int j = 0; j < 8; ++j) ones[j] = (short)0x3F80;   // bf16 1.0

  f32x4 o[4];
  for (int n = 0; n < 4; ++n) o[n] = (f32x4){0.f, 0.f, 0.f, 0.f};
  f32x4 o5 = (f32x4){0.f, 0.f, 0.f, 0.f};                 // rowsum accumulator

  const int srow = lane >> 3;
  const int sc   = ((lane & 7) ^ srow) * 8;
  const u16* kg = k  + (size_t)bh * 65536;
  const u16* vg = vt + (size_t)bh * 65536;

  auto stage = [&](int buf, int kt) {
#pragma unroll
    for (int t = 0; t < 2; ++t) {
      const int seg = w * 2 + t;
      const int rr = seg * 8 + srow;
      GLDS16(kg + (size_t)(kt * 64 + rr) * 64 + sc,  (char*)Ks[buf]  + seg * 1024);
      GLDS16(vg + (size_t)rr * 1024 + kt * 64 + sc,  (char*)VTs[buf] + seg * 1024);
    }
  };

  int cur = 0;
  stage(0, 0);
  for (int kt = 0; kt < 16; ++kt) {
    __syncthreads();
    if (kt < 15) stage(cur ^ 1, kt + 1);

    f32x4 s[4];
#pragma unroll
    for (int n = 0; n < 4; ++n) s[n] = (f32x4){0.f, 0.f, 0.f, 0.f};
#pragma unroll
    for (int n = 0; n < 4; ++n)
#pragma unroll
      for (int kk = 0; kk < 2; ++kk) {
        bf16x8 bk = *(const bf16x8*)(Ks[cur] + (n * 16 + fr) * 64 + (((kk * 4 + hi) ^ (fr & 7)) * 8));
        s[n] = __builtin_amdgcn_mfma_f32_16x16x32_bf16(aq[kk], bk, s[n], 0, 0, 0);
      }

#pragma unroll
    for (int n = 0; n < 4; ++n)
#pragma unroll
      for (int i = 0; i < 4; ++i) {
        const float p = __expf(s[n][i] * 0.125f);
        const int row = hi * 4 + i;
        const int swc = (n * 2 + (fr >> 3)) ^ (row & 7);
        Ps[w][row * 64 + swc * 8 + (fr & 7)] = f2bfr(p);
      }

#pragma unroll
    for (int kk = 0; kk < 2; ++kk) {
      bf16x8 ap = *(const bf16x8*)(&Ps[w][fr * 64 + (((kk * 4 + hi) ^ (fr & 7)) * 8)]);
      o5 = __builtin_amdgcn_mfma_f32_16x16x32_bf16(ap, ones, o5, 0, 0, 0);
#pragma unroll
      for (int n = 0; n < 4; ++n) {
        bf16x8 bv = *(const bf16x8*)(VTs[cur] + (n * 16 + fr) * 64 + (((kk * 4 + hi) ^ (fr & 7)) * 8));
        o[n] = __builtin_amdgcn_mfma_f32_16x16x32_bf16(ap, bv, o[n], 0, 0, 0);
      }
    }
    cur ^= 1;
  }

  float inv[4];
#pragma unroll
  for (int i = 0; i < 4; ++i) inv[i] = 1.f / o5[i];       // o5[i] = rowsum(row hi*4+i)
  const int orow0 = qt * 64 + w * 16 + hi * 4;
#pragma unroll
  for (int n = 0; n < 4; ++n)
#pragma unroll
    for (int i = 0; i < 4; ++i)
      out[((size_t)b * 1024 + orow0 + i) * 768 + h * 64 + n * 16 + fr] = f2bfr(o[n][i] * inv[i]);
}

// ---------------- launch ----------------
extern "C" void kernel_launch(void* const* d_in, const int* in_sizes, int n_in,
                              void* d_out, int out_size, void* d_ws, size_t ws_size,
                              hipStream_t stream)
{
  (void)in_sizes; (void)n_in; (void)out_size; (void)ws_size;
  const float* x      = (const float*)d_in[0];
  const float* qkv_w  = (const float*)d_in[1];
  const float* proj_w = (const float*)d_in[2];
  const float* proj_b = (const float*)d_in[3];
  float* out = (float*)d_out;

  char* p = (char*)d_ws;
  auto take = [&](size_t bytes) { char* r = p; p += (bytes + 255) & ~(size_t)255; return r; };
  u16* xb   = (u16*)take((size_t)8192 * 768 * 2);   // x bf16
  u16* wqb  = (u16*)take((size_t)2304 * 768 * 2);   // qkv_w bf16
  u16* wpb  = (u16*)take((size_t)768 * 768 * 2);    // proj_w bf16
  u16* qraw = (u16*)take((size_t)8192 * 768 * 2);   // q pre-norm [B,H,N,D]
  u16* kraw = (u16*)take((size_t)8192 * 768 * 2);   // k pre-norm [B,H,N,D]
  u16* vtb  = (u16*)take((size_t)8192 * 768 * 2);   // v^T       [B,H,D,N]
  u16* qb   = (u16*)take((size_t)8192 * 768 * 2);   // q normed
  u16* kb   = (u16*)take((size_t)8192 * 768 * 2);   // k normed
  u16* aob  = (u16*)take((size_t)8192 * 768 * 2);   // attn out [B*N, C]

  cvt_f2b4<<<6144, 256, 0, stream>>>(x, xb, 8192 * 768 / 4);
  cvt_f2b4<<<1728, 256, 0, stream>>>(qkv_w, wqb, 2304 * 768 / 4);
  cvt_f2b4<<<576,  256, 0, stream>>>(proj_w, wpb, 768 * 768 / 4);

  gemm_qkv<<<dim3(64, 18), 256, 0, stream>>>(xb, wqb, qraw, kraw, vtb);
  norm_qk<<<6144, 256, 0, stream>>>(qraw, kraw, qb, kb);
  attn_fwd<<<1536, 256, 0, stream>>>(qb, kb, vtb, aob);
  gemm_proj<<<dim3(64, 6), 256, 0, stream>>>(aob, wpb, proj_b, out);
}

// Round 7
// 199.296 us; speedup vs baseline: 1.2884x; 1.0270x over previous
//
#include <hip/hip_runtime.h>
#include <hip/hip_bf16.h>
#include <stdint.h>

typedef unsigned short u16;
typedef __attribute__((ext_vector_type(8))) short bf16x8;
typedef __attribute__((ext_vector_type(4))) float f32x4;

#define GLDS16(gsrc, ldst) \
  __builtin_amdgcn_global_load_lds((const __attribute__((address_space(1))) uint32_t*)(gsrc), \
                                   (__attribute__((address_space(3))) uint32_t*)(ldst), 16, 0, 0)

__device__ __forceinline__ u16 f2bf(float f) {          // round-nearest-even-ish
  unsigned u = __float_as_uint(f);
  return (u16)((u + 0x7fffu + ((u >> 16) & 1u)) >> 16);
}
__device__ __forceinline__ u16 f2bfr(float f) {         // cheap round-away (2 VALU ops)
  return (u16)((__float_as_uint(f) + 0x8000u) >> 16);
}
__device__ __forceinline__ float bf2f(u16 v) {
  return __uint_as_float(((unsigned)v) << 16);
}

// ---------------- fp32 -> bf16 cast, 4 elems/thread ----------------
__global__ void cvt_f2b4(const float* __restrict__ in, u16* __restrict__ out, int n4) {
  int i = blockIdx.x * 256 + threadIdx.x;
  if (i < n4) {
    float4 v = ((const float4*)in)[i];
    ushort4 r;
    r.x = f2bf(v.x); r.y = f2bf(v.y); r.z = f2bf(v.z); r.w = f2bf(v.w);
    ((ushort4*)out)[i] = r;
  }
}

// =====================================================================
// GEMM K-loop (K=768, KT=24): 128x128 tile, BK=32, 4 waves (2x2),
// TRIPLE-buffered LDS, raw s_barrier + counted vmcnt(4).  (R4-proven)
// =====================================================================
#define GEMM_PREAMBLE(AP, BP)                                              \
  __shared__ __align__(16) u16 As[3][128 * 32];                            \
  __shared__ __align__(16) u16 Bs[3][128 * 32];                            \
  const int tid  = threadIdx.x;                                            \
  const int lane = tid & 63;                                               \
  const int w    = tid >> 6;                                               \
  const int wr   = w >> 1, wc = w & 1;                                     \
  const int m0 = blockIdx.x * 128;                                         \
  const int n0 = blockIdx.y * 128;                                         \
  f32x4 acc[4][4];                                                         \
  for (int m = 0; m < 4; ++m)                                              \
    for (int n = 0; n < 4; ++n) acc[m][n] = (f32x4){0.f, 0.f, 0.f, 0.f};   \
  const int rsel = lane >> 2;                                              \
  const int koff = (lane & 3) * 8;                                         \
  const int fr   = lane & 15;                                              \
  const int hi   = lane >> 4;                                              \
  const int fk   = hi * 8;                                                 \
  auto stage = [&](int buf, int kt) {                                      \
    _Pragma("unroll")                                                      \
    for (int t = 0; t < 2; ++t) {                                          \
      const int seg = w * 2 + t;                                           \
      const int rr  = seg * 16 + rsel;                                     \
      GLDS16(AP + (size_t)(m0 + rr) * 768 + kt * 32 + koff,                \
             (char*)As[buf] + seg * 1024);                                 \
      GLDS16(BP + (size_t)(n0 + rr) * 768 + kt * 32 + koff,                \
             (char*)Bs[buf] + seg * 1024);                                 \
    }                                                                      \
  };                                                                       \
  stage(0, 0); stage(1, 1);                                                \
  asm volatile("s_waitcnt vmcnt(4)" ::: "memory");                         \
  __builtin_amdgcn_s_barrier();                                            \
  for (int kt = 0; kt < 24; ++kt) {                                        \
    const int cb = kt % 3;                                                 \
    if (kt + 2 < 24) stage((kt + 2) % 3, kt + 2);                          \
    bf16x8 af[4], bg[4];                                                   \
    _Pragma("unroll")                                                      \
    for (int m = 0; m < 4; ++m)                                            \
      af[m] = *(const bf16x8*)(As[cb] + (wr * 64 + m * 16 + fr) * 32 + fk);\
    _Pragma("unroll")                                                      \
    for (int n = 0; n < 4; ++n)                                            \
      bg[n] = *(const bf16x8*)(Bs[cb] + (wc * 64 + n * 16 + fr) * 32 + fk);\
    _Pragma("unroll")                                                      \
    for (int m = 0; m < 4; ++m)                                            \
      _Pragma("unroll")                                                    \
      for (int n = 0; n < 4; ++n)                                          \
        acc[m][n] = __builtin_amdgcn_mfma_f32_16x16x32_bf16(af[m], bg[n], acc[m][n], 0, 0, 0); \
    if (kt < 23) {                                                         \
      if (kt < 22) asm volatile("s_waitcnt vmcnt(4)" ::: "memory");        \
      else         asm volatile("s_waitcnt vmcnt(0)" ::: "memory");        \
      __builtin_amdgcn_s_barrier();                                        \
    }                                                                      \
  }

// ---- qkv GEMM + FUSED qk-norm + straight V transpose epilogue.
// Each wave's 64 cols = exactly one head. q/k: per-token mean/var over the
// in-wave 4regs x 16lanes row (ddof=1), write normalized bf16 to qb/kb
// [B,H,N,D] (computed from fp32 acc — no intermediate bf16 roundtrip).
// v: straight transpose to vt[B,H,D,N] (R4-proven store pattern).
__global__ __launch_bounds__(256, 3)
void gemm_qkv(const u16* __restrict__ A, const u16* __restrict__ Bm,
              u16* __restrict__ qb, u16* __restrict__ kb, u16* __restrict__ vt)
{
  GEMM_PREAMBLE(A, Bm)
  const int b     = m0 >> 10;
  const int nrow0 = (m0 & 1023) + wr * 64 + hi * 4;
  const int sec   = n0 / 768;                 // 0=q 1=k 2=v
  const int csb   = (n0 % 768) + wc * 64;     // head-aligned (64 | csb)
  const int hh    = csb >> 6;
  if (sec < 2) {
    u16* base = (sec == 0 ? qb : kb) + ((size_t)(b * 12 + hh) << 16);
#pragma unroll
    for (int m = 0; m < 4; ++m)
#pragma unroll
      for (int i = 0; i < 4; ++i) {
        float t0 = acc[m][0][i], t1 = acc[m][1][i], t2 = acc[m][2][i], t3 = acc[m][3][i];
        float sum = (t0 + t1) + (t2 + t3);
        sum += __shfl_xor(sum, 1, 64); sum += __shfl_xor(sum, 2, 64);
        sum += __shfl_xor(sum, 4, 64); sum += __shfl_xor(sum, 8, 64);
        const float mu = sum * (1.f / 64.f);
        t0 -= mu; t1 -= mu; t2 -= mu; t3 -= mu;
        float ss = t0 * t0 + t1 * t1 + t2 * t2 + t3 * t3;
        ss += __shfl_xor(ss, 1, 64); ss += __shfl_xor(ss, 2, 64);
        ss += __shfl_xor(ss, 4, 64); ss += __shfl_xor(ss, 8, 64);
        const float scl = rsqrtf(ss * (1.f / 63.f));
        const size_t rb = (size_t)(nrow0 + m * 16 + i) * 64 + fr;
        base[rb]      = f2bf(t0 * scl);
        base[rb + 16] = f2bf(t1 * scl);
        base[rb + 32] = f2bf(t2 * scl);
        base[rb + 48] = f2bf(t3 * scl);
      }
  } else {
    u16* base = vt + ((size_t)(b * 12 + hh) << 16);
#pragma unroll
    for (int nf = 0; nf < 4; ++nf) {
      const int d = nf * 16 + fr;
#pragma unroll
      for (int m = 0; m < 4; ++m) {
        const int vrow = nrow0 + m * 16;                 // straight (no permute)
        ushort4 pk;
        pk.x = f2bf(acc[m][nf][0]); pk.y = f2bf(acc[m][nf][1]);
        pk.z = f2bf(acc[m][nf][2]); pk.w = f2bf(acc[m][nf][3]);
        *(ushort4*)(base + (size_t)d * 1024 + vrow) = pk;
      }
    }
  }
}

// ---- proj GEMM: A=aob[8192,768], B=wpb[768,768], +bias, fp32 out.
__global__ __launch_bounds__(256, 3)
void gemm_proj(const u16* __restrict__ A, const u16* __restrict__ Bm,
               const float* __restrict__ bias, float* __restrict__ Cout)
{
  GEMM_PREAMBLE(A, Bm)
  const int r0 = m0 + wr * 64 + hi * 4;
  const int c0 = n0 + wc * 64 + fr;
#pragma unroll
  for (int nf = 0; nf < 4; ++nf) {
    const float bv = bias[c0 + nf * 16];
#pragma unroll
    for (int m = 0; m < 4; ++m)
#pragma unroll
      for (int i = 0; i < 4; ++i)
        Cout[(size_t)(r0 + m * 16 + i) * 768 + c0 + nf * 16] = acc[m][nf][i] + bv;
  }
}

// ---------------- flash attention — R4-EXACT (16x16, P via LDS, ones-MFMA rowsum) ----------------
__global__ __launch_bounds__(256, 2)
void attn_fwd(const u16* __restrict__ q, const u16* __restrict__ k,
              const u16* __restrict__ vt, u16* __restrict__ out)
{
  __shared__ __align__(16) u16 Ks[2][64 * 64];
  __shared__ __align__(16) u16 VTs[2][64 * 64];
  __shared__ __align__(16) u16 Ps[4][16 * 64];
  const int tid = threadIdx.x, lane = tid & 63, w = tid >> 6;
  const int bid = (blockIdx.x & 7) * 192 + (blockIdx.x >> 3);
  const int qt = bid & 15;
  const int bh = bid >> 4;
  const int b = bh / 12, h = bh % 12;
  const int fr = lane & 15;
  const int hi = lane >> 4;
  const int fk = hi * 8;

  bf16x8 aq[2];
  {
    const int qrow = qt * 64 + w * 16 + fr;
    const u16* qp = q + ((size_t)bh * 1024 + qrow) * 64;
#pragma unroll
    for (int kk = 0; kk < 2; ++kk)
      aq[kk] = *(const bf16x8*)(qp + kk * 32 + fk);
  }

  bf16x8 ones;
#pragma unroll
  for (int j = 0; j < 8; ++j) ones[j] = (short)0x3F80;   // bf16 1.0

  f32x4 o[4];
  for (int n = 0; n < 4; ++n) o[n] = (f32x4){0.f, 0.f, 0.f, 0.f};
  f32x4 o5 = (f32x4){0.f, 0.f, 0.f, 0.f};                 // rowsum accumulator

  const int srow = lane >> 3;
  const int sc   = ((lane & 7) ^ srow) * 8;
  const u16* kg = k  + (size_t)bh * 65536;
  const u16* vg = vt + (size_t)bh * 65536;

  auto stage = [&](int buf, int kt) {
#pragma unroll
    for (int t = 0; t < 2; ++t) {
      const int seg = w * 2 + t;
      const int rr = seg * 8 + srow;
      GLDS16(kg + (size_t)(kt * 64 + rr) * 64 + sc,  (char*)Ks[buf]  + seg * 1024);
      GLDS16(vg + (size_t)rr * 1024 + kt * 64 + sc,  (char*)VTs[buf] + seg * 1024);
    }
  };

  int cur = 0;
  stage(0, 0);
  for (int kt = 0; kt < 16; ++kt) {
    __syncthreads();
    if (kt < 15) stage(cur ^ 1, kt + 1);

    f32x4 s[4];
#pragma unroll
    for (int n = 0; n < 4; ++n) s[n] = (f32x4){0.f, 0.f, 0.f, 0.f};
#pragma unroll
    for (int n = 0; n < 4; ++n)
#pragma unroll
      for (int kk = 0; kk < 2; ++kk) {
        bf16x8 bk = *(const bf16x8*)(Ks[cur] + (n * 16 + fr) * 64 + (((kk * 4 + hi) ^ (fr & 7)) * 8));
        s[n] = __builtin_amdgcn_mfma_f32_16x16x32_bf16(aq[kk], bk, s[n], 0, 0, 0);
      }

#pragma unroll
    for (int n = 0; n < 4; ++n)
#pragma unroll
      for (int i = 0; i < 4; ++i) {
        const float p = __expf(s[n][i] * 0.125f);
        const int row = hi * 4 + i;
        const int swc = (n * 2 + (fr >> 3)) ^ (row & 7);
        Ps[w][row * 64 + swc * 8 + (fr & 7)] = f2bfr(p);
      }

#pragma unroll
    for (int kk = 0; kk < 2; ++kk) {
      bf16x8 ap = *(const bf16x8*)(&Ps[w][fr * 64 + (((kk * 4 + hi) ^ (fr & 7)) * 8)]);
      o5 = __builtin_amdgcn_mfma_f32_16x16x32_bf16(ap, ones, o5, 0, 0, 0);
#pragma unroll
      for (int n = 0; n < 4; ++n) {
        bf16x8 bv = *(const bf16x8*)(VTs[cur] + (n * 16 + fr) * 64 + (((kk * 4 + hi) ^ (fr & 7)) * 8));
        o[n] = __builtin_amdgcn_mfma_f32_16x16x32_bf16(ap, bv, o[n], 0, 0, 0);
      }
    }
    cur ^= 1;
  }

  float inv[4];
#pragma unroll
  for (int i = 0; i < 4; ++i) inv[i] = 1.f / o5[i];
  const int orow0 = qt * 64 + w * 16 + hi * 4;
#pragma unroll
  for (int n = 0; n < 4; ++n)
#pragma unroll
    for (int i = 0; i < 4; ++i)
      out[((size_t)b * 1024 + orow0 + i) * 768 + h * 64 + n * 16 + fr] = f2bfr(o[n][i] * inv[i]);
}

// ---------------- launch ----------------
extern "C" void kernel_launch(void* const* d_in, const int* in_sizes, int n_in,
                              void* d_out, int out_size, void* d_ws, size_t ws_size,
                              hipStream_t stream)
{
  (void)in_sizes; (void)n_in; (void)out_size; (void)ws_size;
  const float* x      = (const float*)d_in[0];
  const float* qkv_w  = (const float*)d_in[1];
  const float* proj_w = (const float*)d_in[2];
  const float* proj_b = (const float*)d_in[3];
  float* out = (float*)d_out;

  char* p = (char*)d_ws;
  auto take = [&](size_t bytes) { char* r = p; p += (bytes + 255) & ~(size_t)255; return r; };
  u16* xb   = (u16*)take((size_t)8192 * 768 * 2);   // x bf16
  u16* wqb  = (u16*)take((size_t)2304 * 768 * 2);   // qkv_w bf16
  u16* wpb  = (u16*)take((size_t)768 * 768 * 2);    // proj_w bf16
  u16* qb   = (u16*)take((size_t)8192 * 768 * 2);   // q normed [B,H,N,D]
  u16* kb   = (u16*)take((size_t)8192 * 768 * 2);   // k normed [B,H,N,D]
  u16* vtb  = (u16*)take((size_t)8192 * 768 * 2);   // v^T      [B,H,D,N]
  u16* aob  = (u16*)take((size_t)8192 * 768 * 2);   // attn out [B*N, C]

  cvt_f2b4<<<6144, 256, 0, stream>>>(x, xb, 8192 * 768 / 4);
  cvt_f2b4<<<1728, 256, 0, stream>>>(qkv_w, wqb, 2304 * 768 / 4);
  cvt_f2b4<<<576,  256, 0, stream>>>(proj_w, wpb, 768 * 768 / 4);

  gemm_qkv<<<dim3(64, 18), 256, 0, stream>>>(xb, wqb, qb, kb, vtb);
  attn_fwd<<<1536, 256, 0, stream>>>(qb, kb, vtb, aob);
  gemm_proj<<<dim3(64, 6), 256, 0, stream>>>(aob, wpb, proj_b, out);
}

// Round 8
// 198.409 us; speedup vs baseline: 1.2942x; 1.0045x over previous
//
#include <hip/hip_runtime.h>
#include <hip/hip_bf16.h>
#include <stdint.h>

typedef unsigned short u16;
typedef __attribute__((ext_vector_type(8))) short bf16x8;
typedef __attribute__((ext_vector_type(4))) float f32x4;

#define GLDS16(gsrc, ldst) \
  __builtin_amdgcn_global_load_lds((const __attribute__((address_space(1))) uint32_t*)(gsrc), \
                                   (__attribute__((address_space(3))) uint32_t*)(ldst), 16, 0, 0)

__device__ __forceinline__ u16 f2bf(float f) {          // round-nearest-even-ish
  unsigned u = __float_as_uint(f);
  return (u16)((u + 0x7fffu + ((u >> 16) & 1u)) >> 16);
}
__device__ __forceinline__ u16 f2bfr(float f) {         // cheap round-away (2 VALU ops)
  return (u16)((__float_as_uint(f) + 0x8000u) >> 16);
}
__device__ __forceinline__ float bf2f(u16 v) {
  return __uint_as_float(((unsigned)v) << 16);
}

// ---------------- fp32 -> bf16 cast, 4 elems/thread ----------------
__global__ void cvt_f2b4(const float* __restrict__ in, u16* __restrict__ out, int n4) {
  int i = blockIdx.x * 256 + threadIdx.x;
  if (i < n4) {
    float4 v = ((const float4*)in)[i];
    ushort4 r;
    r.x = f2bf(v.x); r.y = f2bf(v.y); r.z = f2bf(v.z); r.w = f2bf(v.w);
    ((ushort4*)out)[i] = r;
  }
}

// =====================================================================
// GEMM K-loop (K=768, KT=24): 128x128 tile, BK=32, 4 waves (2x2),
// TRIPLE-buffered LDS, raw s_barrier + counted vmcnt(4).  (R4-proven)
// R7: + T2 chunk swizzle — 16B chunk c of row r lives at slot c^((r>>1)&3).
// Staging keeps LDS dest linear; global SOURCE chunk pre-swizzled (rule #21).
// Bank math: frag read bank-start = (r&1)*16 + slot*4 -> lanes fr,fr+8 alone
// share a combo -> 2-way (free, m136) instead of 8-way.
// =====================================================================
#define GEMM_PREAMBLE(AP, BP)                                              \
  __shared__ __align__(16) u16 As[3][128 * 32];                            \
  __shared__ __align__(16) u16 Bs[3][128 * 32];                            \
  const int tid  = threadIdx.x;                                            \
  const int lane = tid & 63;                                               \
  const int w    = tid >> 6;                                               \
  const int wr   = w >> 1, wc = w & 1;                                     \
  const int m0 = blockIdx.x * 128;                                         \
  const int n0 = blockIdx.y * 128;                                         \
  f32x4 acc[4][4];                                                         \
  for (int m = 0; m < 4; ++m)                                              \
    for (int n = 0; n < 4; ++n) acc[m][n] = (f32x4){0.f, 0.f, 0.f, 0.f};   \
  const int rsel = lane >> 2;                                              \
  const int koff = (((lane & 3) ^ ((lane >> 3) & 3))) * 8;                 \
  const int fr   = lane & 15;                                              \
  const int hi   = lane >> 4;                                              \
  const int slot = (hi ^ ((fr >> 1) & 3)) * 8;                             \
  auto stage = [&](int buf, int kt) {                                      \
    _Pragma("unroll")                                                      \
    for (int t = 0; t < 2; ++t) {                                          \
      const int seg = w * 2 + t;                                           \
      const int rr  = seg * 16 + rsel;                                     \
      GLDS16(AP + (size_t)(m0 + rr) * 768 + kt * 32 + koff,                \
             (char*)As[buf] + seg * 1024);                                 \
      GLDS16(BP + (size_t)(n0 + rr) * 768 + kt * 32 + koff,                \
             (char*)Bs[buf] + seg * 1024);                                 \
    }                                                                      \
  };                                                                       \
  stage(0, 0); stage(1, 1);                                                \
  asm volatile("s_waitcnt vmcnt(4)" ::: "memory");                         \
  __builtin_amdgcn_s_barrier();                                            \
  for (int kt = 0; kt < 24; ++kt) {                                        \
    const int cb = kt % 3;                                                 \
    if (kt + 2 < 24) stage((kt + 2) % 3, kt + 2);                          \
    bf16x8 af[4], bg[4];                                                   \
    _Pragma("unroll")                                                      \
    for (int m = 0; m < 4; ++m)                                            \
      af[m] = *(const bf16x8*)(As[cb] + (wr * 64 + m * 16 + fr) * 32 + slot);\
    _Pragma("unroll")                                                      \
    for (int n = 0; n < 4; ++n)                                            \
      bg[n] = *(const bf16x8*)(Bs[cb] + (wc * 64 + n * 16 + fr) * 32 + slot);\
    _Pragma("unroll")                                                      \
    for (int m = 0; m < 4; ++m)                                            \
      _Pragma("unroll")                                                    \
      for (int n = 0; n < 4; ++n)                                          \
        acc[m][n] = __builtin_amdgcn_mfma_f32_16x16x32_bf16(af[m], bg[n], acc[m][n], 0, 0, 0); \
    if (kt < 23) {                                                         \
      if (kt < 22) asm volatile("s_waitcnt vmcnt(4)" ::: "memory");        \
      else         asm volatile("s_waitcnt vmcnt(0)" ::: "memory");        \
      __builtin_amdgcn_s_barrier();                                        \
    }                                                                      \
  }

// ---- qkv GEMM + FUSED qk-norm + straight V transpose epilogue.
// q/k: per-token mean/var (ddof=1) over the in-wave row, then stored with
// d-PERMUTED layout d' = 4*(d&15) + (d>>4)  ->  lane's 4 values form one
// coalesced ushort4 at col 4*fr. QK^T is invariant: Q and K get the SAME
// d-permutation and attn consumes rows as opaque 64-vectors on both operands.
// v: straight transpose to vt[B,H,D,N] (R4-proven store pattern).
__global__ __launch_bounds__(256, 3)
void gemm_qkv(const u16* __restrict__ A, const u16* __restrict__ Bm,
              u16* __restrict__ qb, u16* __restrict__ kb, u16* __restrict__ vt)
{
  GEMM_PREAMBLE(A, Bm)
  const int b     = m0 >> 10;
  const int nrow0 = (m0 & 1023) + wr * 64 + hi * 4;
  const int sec   = n0 / 768;                 // 0=q 1=k 2=v
  const int csb   = (n0 % 768) + wc * 64;     // head-aligned (64 | csb)
  const int hh    = csb >> 6;
  if (sec < 2) {
    u16* base = (sec == 0 ? qb : kb) + ((size_t)(b * 12 + hh) << 16);
#pragma unroll
    for (int m = 0; m < 4; ++m)
#pragma unroll
      for (int i = 0; i < 4; ++i) {
        float t0 = acc[m][0][i], t1 = acc[m][1][i], t2 = acc[m][2][i], t3 = acc[m][3][i];
        float sum = (t0 + t1) + (t2 + t3);
        sum += __shfl_xor(sum, 1, 64); sum += __shfl_xor(sum, 2, 64);
        sum += __shfl_xor(sum, 4, 64); sum += __shfl_xor(sum, 8, 64);
        const float mu = sum * (1.f / 64.f);
        t0 -= mu; t1 -= mu; t2 -= mu; t3 -= mu;
        float ss = t0 * t0 + t1 * t1 + t2 * t2 + t3 * t3;
        ss += __shfl_xor(ss, 1, 64); ss += __shfl_xor(ss, 2, 64);
        ss += __shfl_xor(ss, 4, 64); ss += __shfl_xor(ss, 8, 64);
        const float scl = rsqrtf(ss * (1.f / 63.f));
        ushort4 pk;                                   // d' = 4*fr + s
        pk.x = f2bf(t0 * scl); pk.y = f2bf(t1 * scl);
        pk.z = f2bf(t2 * scl); pk.w = f2bf(t3 * scl);
        *(ushort4*)(base + (size_t)(nrow0 + m * 16 + i) * 64 + fr * 4) = pk;
      }
  } else {
    u16* base = vt + ((size_t)(b * 12 + hh) << 16);
#pragma unroll
    for (int nf = 0; nf < 4; ++nf) {
      const int d = nf * 16 + fr;
#pragma unroll
      for (int m = 0; m < 4; ++m) {
        const int vrow = nrow0 + m * 16;                 // straight (no permute)
        ushort4 pk;
        pk.x = f2bf(acc[m][nf][0]); pk.y = f2bf(acc[m][nf][1]);
        pk.z = f2bf(acc[m][nf][2]); pk.w = f2bf(acc[m][nf][3]);
        *(ushort4*)(base + (size_t)d * 1024 + vrow) = pk;
      }
    }
  }
}

// ---- proj GEMM: A=aob[8192,768], B=wpb[768,768], +bias, fp32 out.
__global__ __launch_bounds__(256, 3)
void gemm_proj(const u16* __restrict__ A, const u16* __restrict__ Bm,
               const float* __restrict__ bias, float* __restrict__ Cout)
{
  GEMM_PREAMBLE(A, Bm)
  const int r0 = m0 + wr * 64 + hi * 4;
  const int c0 = n0 + wc * 64 + fr;
#pragma unroll
  for (int nf = 0; nf < 4; ++nf) {
    const float bv = bias[c0 + nf * 16];
#pragma unroll
    for (int m = 0; m < 4; ++m)
#pragma unroll
      for (int i = 0; i < 4; ++i)
        Cout[(size_t)(r0 + m * 16 + i) * 768 + c0 + nf * 16] = acc[m][nf][i] + bv;
  }
}

// ---------------- flash attention — R4 structure, occupancy 4 blocks/CU ----------------
__global__ __launch_bounds__(256, 4)
void attn_fwd(const u16* __restrict__ q, const u16* __restrict__ k,
              const u16* __restrict__ vt, u16* __restrict__ out)
{
  __shared__ __align__(16) u16 Ks[2][64 * 64];
  __shared__ __align__(16) u16 VTs[2][64 * 64];
  __shared__ __align__(16) u16 Ps[4][16 * 64];
  const int tid = threadIdx.x, lane = tid & 63, w = tid >> 6;
  const int bid = (blockIdx.x & 7) * 192 + (blockIdx.x >> 3);
  const int qt = bid & 15;
  const int bh = bid >> 4;
  const int b = bh / 12, h = bh % 12;
  const int fr = lane & 15;
  const int hi = lane >> 4;
  const int fk = hi * 8;

  bf16x8 aq[2];
  {
    const int qrow = qt * 64 + w * 16 + fr;
    const u16* qp = q + ((size_t)bh * 1024 + qrow) * 64;
#pragma unroll
    for (int kk = 0; kk < 2; ++kk)
      aq[kk] = *(const bf16x8*)(qp + kk * 32 + fk);
  }

  bf16x8 ones;
#pragma unroll
  for (int j = 0; j < 8; ++j) ones[j] = (short)0x3F80;   // bf16 1.0

  f32x4 o[4];
  for (int n = 0; n < 4; ++n) o[n] = (f32x4){0.f, 0.f, 0.f, 0.f};
  f32x4 o5 = (f32x4){0.f, 0.f, 0.f, 0.f};                 // rowsum accumulator

  const int srow = lane >> 3;
  const int sc   = ((lane & 7) ^ srow) * 8;
  const u16* kg = k  + (size_t)bh * 65536;
  const u16* vg = vt + (size_t)bh * 65536;

  auto stage = [&](int buf, int kt) {
#pragma unroll
    for (int t = 0; t < 2; ++t) {
      const int seg = w * 2 + t;
      const int rr = seg * 8 + srow;
      GLDS16(kg + (size_t)(kt * 64 + rr) * 64 + sc,  (char*)Ks[buf]  + seg * 1024);
      GLDS16(vg + (size_t)rr * 1024 + kt * 64 + sc,  (char*)VTs[buf] + seg * 1024);
    }
  };

  int cur = 0;
  stage(0, 0);
  for (int kt = 0; kt < 16; ++kt) {
    __syncthreads();
    if (kt < 15) stage(cur ^ 1, kt + 1);

    f32x4 s[4];
#pragma unroll
    for (int n = 0; n < 4; ++n) s[n] = (f32x4){0.f, 0.f, 0.f, 0.f};
#pragma unroll
    for (int n = 0; n < 4; ++n)
#pragma unroll
      for (int kk = 0; kk < 2; ++kk) {
        bf16x8 bk = *(const bf16x8*)(Ks[cur] + (n * 16 + fr) * 64 + (((kk * 4 + hi) ^ (fr & 7)) * 8));
        s[n] = __builtin_amdgcn_mfma_f32_16x16x32_bf16(aq[kk], bk, s[n], 0, 0, 0);
      }

#pragma unroll
    for (int n = 0; n < 4; ++n)
#pragma unroll
      for (int i = 0; i < 4; ++i) {
        const float p = __expf(s[n][i] * 0.125f);
        const int row = hi * 4 + i;
        const int swc = (n * 2 + (fr >> 3)) ^ (row & 7);
        Ps[w][row * 64 + swc * 8 + (fr & 7)] = f2bfr(p);
      }

#pragma unroll
    for (int kk = 0; kk < 2; ++kk) {
      bf16x8 ap = *(const bf16x8*)(&Ps[w][fr * 64 + (((kk * 4 + hi) ^ (fr & 7)) * 8)]);
      o5 = __builtin_amdgcn_mfma_f32_16x16x32_bf16(ap, ones, o5, 0, 0, 0);
#pragma unroll
      for (int n = 0; n < 4; ++n) {
        bf16x8 bv = *(const bf16x8*)(VTs[cur] + (n * 16 + fr) * 64 + (((kk * 4 + hi) ^ (fr & 7)) * 8));
        o[n] = __builtin_amdgcn_mfma_f32_16x16x32_bf16(ap, bv, o[n], 0, 0, 0);
      }
    }
    cur ^= 1;
  }

  float inv[4];
#pragma unroll
  for (int i = 0; i < 4; ++i) inv[i] = 1.f / o5[i];
  const int orow0 = qt * 64 + w * 16 + hi * 4;
#pragma unroll
  for (int n = 0; n < 4; ++n)
#pragma unroll
    for (int i = 0; i < 4; ++i)
      out[((size_t)b * 1024 + orow0 + i) * 768 + h * 64 + n * 16 + fr] = f2bfr(o[n][i] * inv[i]);
}

// ---------------- launch ----------------
extern "C" void kernel_launch(void* const* d_in, const int* in_sizes, int n_in,
                              void* d_out, int out_size, void* d_ws, size_t ws_size,
                              hipStream_t stream)
{
  (void)in_sizes; (void)n_in; (void)out_size; (void)ws_size;
  const float* x      = (const float*)d_in[0];
  const float* qkv_w  = (const float*)d_in[1];
  const float* proj_w = (const float*)d_in[2];
  const float* proj_b = (const float*)d_in[3];
  float* out = (float*)d_out;

  char* p = (char*)d_ws;
  auto take = [&](size_t bytes) { char* r = p; p += (bytes + 255) & ~(size_t)255; return r; };
  u16* xb   = (u16*)take((size_t)8192 * 768 * 2);   // x bf16
  u16* wqb  = (u16*)take((size_t)2304 * 768 * 2);   // qkv_w bf16
  u16* wpb  = (u16*)take((size_t)768 * 768 * 2);    // proj_w bf16
  u16* qb   = (u16*)take((size_t)8192 * 768 * 2);   // q normed [B,H,N,D'] (d-permuted)
  u16* kb   = (u16*)take((size_t)8192 * 768 * 2);   // k normed [B,H,N,D'] (d-permuted)
  u16* vtb  = (u16*)take((size_t)8192 * 768 * 2);   // v^T      [B,H,D,N]
  u16* aob  = (u16*)take((size_t)8192 * 768 * 2);   // attn out [B*N, C]

  cvt_f2b4<<<6144, 256, 0, stream>>>(x, xb, 8192 * 768 / 4);
  cvt_f2b4<<<1728, 256, 0, stream>>>(qkv_w, wqb, 2304 * 768 / 4);
  cvt_f2b4<<<576,  256, 0, stream>>>(proj_w, wpb, 768 * 768 / 4);

  gemm_qkv<<<dim3(64, 18), 256, 0, stream>>>(xb, wqb, qb, kb, vtb);
  attn_fwd<<<1536, 256, 0, stream>>>(qb, kb, vtb, aob);
  gemm_proj<<<dim3(64, 6), 256, 0, stream>>>(aob, wpb, proj_b, out);
}

// Round 10
// 195.431 us; speedup vs baseline: 1.3139x; 1.0152x over previous
//
#include <hip/hip_runtime.h>
#include <hip/hip_bf16.h>
#include <stdint.h>

typedef unsigned short u16;
typedef __attribute__((ext_vector_type(8))) short bf16x8;
typedef __attribute__((ext_vector_type(4))) float f32x4;

#define GLDS16(gsrc, ldst) \
  __builtin_amdgcn_global_load_lds((const __attribute__((address_space(1))) uint32_t*)(gsrc), \
                                   (__attribute__((address_space(3))) uint32_t*)(ldst), 16, 0, 0)

__device__ __forceinline__ u16 f2bf(float f) {          // round-nearest-even-ish
  unsigned u = __float_as_uint(f);
  return (u16)((u + 0x7fffu + ((u >> 16) & 1u)) >> 16);
}
__device__ __forceinline__ u16 f2bfr(float f) {         // cheap round-away (2 VALU ops)
  return (u16)((__float_as_uint(f) + 0x8000u) >> 16);
}
__device__ __forceinline__ float bf2f(u16 v) {
  return __uint_as_float(((unsigned)v) << 16);
}

// ---------------- fused fp32 -> bf16 cast of all three inputs (1 launch) ----------------
// float4 chunks: x 1572864 | qkv_w 442368 | proj_w 147456  (total 2162688)
__global__ void cvt_all(const float* __restrict__ x, const float* __restrict__ wq,
                        const float* __restrict__ wp, u16* __restrict__ xb,
                        u16* __restrict__ wqb, u16* __restrict__ wpb) {
  int i = blockIdx.x * 256 + threadIdx.x;
  const float* src; u16* dst; int off;
  if (i < 1572864)       { src = x;  dst = xb;  off = i; }
  else if (i < 2015232)  { src = wq; dst = wqb; off = i - 1572864; }
  else if (i < 2162688)  { src = wp; dst = wpb; off = i - 2015232; }
  else return;
  float4 v = ((const float4*)src)[off];
  ushort4 r;
  r.x = f2bf(v.x); r.y = f2bf(v.y); r.z = f2bf(v.z); r.w = f2bf(v.w);
  ((ushort4*)dst)[off] = r;
}

// =====================================================================
// GEMM K-loop (K=768, KT=24): 128x128 tile, BK=32, 4 waves (2x2),
// TRIPLE-buffered LDS, raw s_barrier + counted vmcnt(4).  (R4-proven)
// R9: staging/read swizzle REVERTED to R7 linear (R8 measured: swizzle
// eliminated the 8-way ds_read conflict but slowed the staging DMA ~11% —
// conflicts are off the critical path in this counted-vmcnt structure).
// =====================================================================
#define GEMM_PREAMBLE(AP, BP)                                              \
  __shared__ __align__(16) u16 As[3][128 * 32];                            \
  __shared__ __align__(16) u16 Bs[3][128 * 32];                            \
  const int tid  = threadIdx.x;                                            \
  const int lane = tid & 63;                                               \
  const int w    = tid >> 6;                                               \
  const int wr   = w >> 1, wc = w & 1;                                     \
  const int m0 = blockIdx.x * 128;                                         \
  const int n0 = blockIdx.y * 128;                                         \
  f32x4 acc[4][4];                                                         \
  for (int m = 0; m < 4; ++m)                                              \
    for (int n = 0; n < 4; ++n) acc[m][n] = (f32x4){0.f, 0.f, 0.f, 0.f};   \
  const int rsel = lane >> 2;                                              \
  const int koff = (lane & 3) * 8;                                         \
  const int fr   = lane & 15;                                              \
  const int hi   = lane >> 4;                                              \
  const int fk   = hi * 8;                                                 \
  auto stage = [&](int buf, int kt) {                                      \
    _Pragma("unroll")                                                      \
    for (int t = 0; t < 2; ++t) {                                          \
      const int seg = w * 2 + t;                                           \
      const int rr  = seg * 16 + rsel;                                     \
      GLDS16(AP + (size_t)(m0 + rr) * 768 + kt * 32 + koff,                \
             (char*)As[buf] + seg * 1024);                                 \
      GLDS16(BP + (size_t)(n0 + rr) * 768 + kt * 32 + koff,                \
             (char*)Bs[buf] + seg * 1024);                                 \
    }                                                                      \
  };                                                                       \
  stage(0, 0); stage(1, 1);                                                \
  asm volatile("s_waitcnt vmcnt(4)" ::: "memory");                         \
  __builtin_amdgcn_s_barrier();                                            \
  for (int kt = 0; kt < 24; ++kt) {                                        \
    const int cb = kt % 3;                                                 \
    if (kt + 2 < 24) stage((kt + 2) % 3, kt + 2);                          \
    bf16x8 af[4], bg[4];                                                   \
    _Pragma("unroll")                                                      \
    for (int m = 0; m < 4; ++m)                                            \
      af[m] = *(const bf16x8*)(As[cb] + (wr * 64 + m * 16 + fr) * 32 + fk);\
    _Pragma("unroll")                                                      \
    for (int n = 0; n < 4; ++n)                                            \
      bg[n] = *(const bf16x8*)(Bs[cb] + (wc * 64 + n * 16 + fr) * 32 + fk);\
    _Pragma("unroll")                                                      \
    for (int m = 0; m < 4; ++m)                                            \
      _Pragma("unroll")                                                    \
      for (int n = 0; n < 4; ++n)                                          \
        acc[m][n] = __builtin_amdgcn_mfma_f32_16x16x32_bf16(af[m], bg[n], acc[m][n], 0, 0, 0); \
    if (kt < 23) {                                                         \
      if (kt < 22) asm volatile("s_waitcnt vmcnt(4)" ::: "memory");        \
      else         asm volatile("s_waitcnt vmcnt(0)" ::: "memory");        \
      __builtin_amdgcn_s_barrier();                                        \
    }                                                                      \
  }

// ---- qkv GEMM + FUSED qk-norm + straight V transpose epilogue.
// q/k: per-token mean/var (ddof=1), stored with d-PERMUTED layout
// d' = 4*(d&15) + (d>>4) -> lane's 4 values form one coalesced ushort4.
// QK^T invariant: Q and K get the SAME permutation; attn consumes rows as
// opaque 64-vectors on both operands.  v: straight transpose to vt[B,H,D,N].
__global__ __launch_bounds__(256, 3)
void gemm_qkv(const u16* __restrict__ A, const u16* __restrict__ Bm,
              u16* __restrict__ qb, u16* __restrict__ kb, u16* __restrict__ vt)
{
  GEMM_PREAMBLE(A, Bm)
  const int b     = m0 >> 10;
  const int nrow0 = (m0 & 1023) + wr * 64 + hi * 4;
  const int sec   = n0 / 768;                 // 0=q 1=k 2=v
  const int csb   = (n0 % 768) + wc * 64;     // head-aligned (64 | csb)
  const int hh    = csb >> 6;
  if (sec < 2) {
    u16* base = (sec == 0 ? qb : kb) + ((size_t)(b * 12 + hh) << 16);
#pragma unroll
    for (int m = 0; m < 4; ++m)
#pragma unroll
      for (int i = 0; i < 4; ++i) {
        float t0 = acc[m][0][i], t1 = acc[m][1][i], t2 = acc[m][2][i], t3 = acc[m][3][i];
        float sum = (t0 + t1) + (t2 + t3);
        sum += __shfl_xor(sum, 1, 64); sum += __shfl_xor(sum, 2, 64);
        sum += __shfl_xor(sum, 4, 64); sum += __shfl_xor(sum, 8, 64);
        const float mu = sum * (1.f / 64.f);
        t0 -= mu; t1 -= mu; t2 -= mu; t3 -= mu;
        float ss = t0 * t0 + t1 * t1 + t2 * t2 + t3 * t3;
        ss += __shfl_xor(ss, 1, 64); ss += __shfl_xor(ss, 2, 64);
        ss += __shfl_xor(ss, 4, 64); ss += __shfl_xor(ss, 8, 64);
        const float scl = rsqrtf(ss * (1.f / 63.f));
        ushort4 pk;                                   // d' = 4*fr + s
        pk.x = f2bf(t0 * scl); pk.y = f2bf(t1 * scl);
        pk.z = f2bf(t2 * scl); pk.w = f2bf(t3 * scl);
        *(ushort4*)(base + (size_t)(nrow0 + m * 16 + i) * 64 + fr * 4) = pk;
      }
  } else {
    u16* base = vt + ((size_t)(b * 12 + hh) << 16);
#pragma unroll
    for (int nf = 0; nf < 4; ++nf) {
      const int d = nf * 16 + fr;
#pragma unroll
      for (int m = 0; m < 4; ++m) {
        const int vrow = nrow0 + m * 16;                 // straight (no permute)
        ushort4 pk;
        pk.x = f2bf(acc[m][nf][0]); pk.y = f2bf(acc[m][nf][1]);
        pk.z = f2bf(acc[m][nf][2]); pk.w = f2bf(acc[m][nf][3]);
        *(ushort4*)(base + (size_t)d * 1024 + vrow) = pk;
      }
    }
  }
}

// ---- proj GEMM: A=aob[8192,768], B=wpb[768,768], +bias, fp32 out.
__global__ __launch_bounds__(256, 3)
void gemm_proj(const u16* __restrict__ A, const u16* __restrict__ Bm,
               const float* __restrict__ bias, float* __restrict__ Cout)
{
  GEMM_PREAMBLE(A, Bm)
  const int r0 = m0 + wr * 64 + hi * 4;
  const int c0 = n0 + wc * 64 + fr;
#pragma unroll
  for (int nf = 0; nf < 4; ++nf) {
    const float bv = bias[c0 + nf * 16];
#pragma unroll
    for (int m = 0; m < 4; ++m)
#pragma unroll
      for (int i = 0; i < 4; ++i)
        Cout[(size_t)(r0 + m * 16 + i) * 768 + c0 + nf * 16] = acc[m][nf][i] + bv;
  }
}

// ---------------- flash attention — R8 structure + T5 setprio on MFMA clusters ----------------
__global__ __launch_bounds__(256, 4)
void attn_fwd(const u16* __restrict__ q, const u16* __restrict__ k,
              const u16* __restrict__ vt, u16* __restrict__ out)
{
  __shared__ __align__(16) u16 Ks[2][64 * 64];
  __shared__ __align__(16) u16 VTs[2][64 * 64];
  __shared__ __align__(16) u16 Ps[4][16 * 64];
  const int tid = threadIdx.x, lane = tid & 63, w = tid >> 6;
  const int bid = (blockIdx.x & 7) * 192 + (blockIdx.x >> 3);
  const int qt = bid & 15;
  const int bh = bid >> 4;
  const int b = bh / 12, h = bh % 12;
  const int fr = lane & 15;
  const int hi = lane >> 4;
  const int fk = hi * 8;

  bf16x8 aq[2];
  {
    const int qrow = qt * 64 + w * 16 + fr;
    const u16* qp = q + ((size_t)bh * 1024 + qrow) * 64;
#pragma unroll
    for (int kk = 0; kk < 2; ++kk)
      aq[kk] = *(const bf16x8*)(qp + kk * 32 + fk);
  }

  bf16x8 ones;
#pragma unroll
  for (int j = 0; j < 8; ++j) ones[j] = (short)0x3F80;   // bf16 1.0

  f32x4 o[4];
  for (int n = 0; n < 4; ++n) o[n] = (f32x4){0.f, 0.f, 0.f, 0.f};
  f32x4 o5 = (f32x4){0.f, 0.f, 0.f, 0.f};                 // rowsum accumulator

  const int srow = lane >> 3;
  const int sc   = ((lane & 7) ^ srow) * 8;
  const u16* kg = k  + (size_t)bh * 65536;
  const u16* vg = vt + (size_t)bh * 65536;

  auto stage = [&](int buf, int kt) {
#pragma unroll
    for (int t = 0; t < 2; ++t) {
      const int seg = w * 2 + t;
      const int rr = seg * 8 + srow;
      GLDS16(kg + (size_t)(kt * 64 + rr) * 64 + sc,  (char*)Ks[buf]  + seg * 1024);
      GLDS16(vg + (size_t)rr * 1024 + kt * 64 + sc,  (char*)VTs[buf] + seg * 1024);
    }
  };

  int cur = 0;
  stage(0, 0);
  for (int kt = 0; kt < 16; ++kt) {
    __syncthreads();
    if (kt < 15) stage(cur ^ 1, kt + 1);

    f32x4 s[4];
#pragma unroll
    for (int n = 0; n < 4; ++n) s[n] = (f32x4){0.f, 0.f, 0.f, 0.f};
    __builtin_amdgcn_s_setprio(1);
#pragma unroll
    for (int n = 0; n < 4; ++n)
#pragma unroll
      for (int kk = 0; kk < 2; ++kk) {
        bf16x8 bk = *(const bf16x8*)(Ks[cur] + (n * 16 + fr) * 64 + (((kk * 4 + hi) ^ (fr & 7)) * 8));
        s[n] = __builtin_amdgcn_mfma_f32_16x16x32_bf16(aq[kk], bk, s[n], 0, 0, 0);
      }
    __builtin_amdgcn_s_setprio(0);

#pragma unroll
    for (int n = 0; n < 4; ++n)
#pragma unroll
      for (int i = 0; i < 4; ++i) {
        const float p = __expf(s[n][i] * 0.125f);
        const int row = hi * 4 + i;
        const int swc = (n * 2 + (fr >> 3)) ^ (row & 7);
        Ps[w][row * 64 + swc * 8 + (fr & 7)] = f2bfr(p);
      }

    __builtin_amdgcn_s_setprio(1);
#pragma unroll
    for (int kk = 0; kk < 2; ++kk) {
      bf16x8 ap = *(const bf16x8*)(&Ps[w][fr * 64 + (((kk * 4 + hi) ^ (fr & 7)) * 8)]);
      o5 = __builtin_amdgcn_mfma_f32_16x16x32_bf16(ap, ones, o5, 0, 0, 0);
#pragma unroll
      for (int n = 0; n < 4; ++n) {
        bf16x8 bv = *(const bf16x8*)(VTs[cur] + (n * 16 + fr) * 64 + (((kk * 4 + hi) ^ (fr & 7)) * 8));
        o[n] = __builtin_amdgcn_mfma_f32_16x16x32_bf16(ap, bv, o[n], 0, 0, 0);
      }
    }
    __builtin_amdgcn_s_setprio(0);
    cur ^= 1;
  }

  float inv[4];
#pragma unroll
  for (int i = 0; i < 4; ++i) inv[i] = 1.f / o5[i];
  const int orow0 = qt * 64 + w * 16 + hi * 4;
#pragma unroll
  for (int n = 0; n < 4; ++n)
#pragma unroll
    for (int i = 0; i < 4; ++i)
      out[((size_t)b * 1024 + orow0 + i) * 768 + h * 64 + n * 16 + fr] = f2bfr(o[n][i] * inv[i]);
}

// ---------------- launch ----------------
extern "C" void kernel_launch(void* const* d_in, const int* in_sizes, int n_in,
                              void* d_out, int out_size, void* d_ws, size_t ws_size,
                              hipStream_t stream)
{
  (void)in_sizes; (void)n_in; (void)out_size; (void)ws_size;
  const float* x      = (const float*)d_in[0];
  const float* qkv_w  = (const float*)d_in[1];
  const float* proj_w = (const float*)d_in[2];
  const float* proj_b = (const float*)d_in[3];
  float* out = (float*)d_out;

  char* p = (char*)d_ws;
  auto take = [&](size_t bytes) { char* r = p; p += (bytes + 255) & ~(size_t)255; return r; };
  u16* xb   = (u16*)take((size_t)8192 * 768 * 2);   // x bf16
  u16* wqb  = (u16*)take((size_t)2304 * 768 * 2);   // qkv_w bf16
  u16* wpb  = (u16*)take((size_t)768 * 768 * 2);    // proj_w bf16
  u16* qb   = (u16*)take((size_t)8192 * 768 * 2);   // q normed [B,H,N,D'] (d-permuted)
  u16* kb   = (u16*)take((size_t)8192 * 768 * 2);   // k normed [B,H,N,D'] (d-permuted)
  u16* vtb  = (u16*)take((size_t)8192 * 768 * 2);   // v^T      [B,H,D,N]
  u16* aob  = (u16*)take((size_t)8192 * 768 * 2);   // attn out [B*N, C]

  cvt_all<<<8448, 256, 0, stream>>>(x, qkv_w, proj_w, xb, wqb, wpb);
  gemm_qkv<<<dim3(64, 18), 256, 0, stream>>>(xb, wqb, qb, kb, vtb);
  attn_fwd<<<1536, 256, 0, stream>>>(qb, kb, vtb, aob);
  gemm_proj<<<dim3(64, 6), 256, 0, stream>>>(aob, wpb, proj_b, out);
}